// Round 7
// baseline (263.278 us; speedup 1.0000x reference)
//
#include <hip/hip_runtime.h>
#include <hip/hip_bf16.h>

#define EMB 768
#define HD 96
#define NH 8
#define SEQ 2048
#define SCALING 0.10206207261596575f   // 96^-0.5

typedef short bf16x8 __attribute__((ext_vector_type(8)));
typedef float f32x4  __attribute__((ext_vector_type(4)));
typedef unsigned short u16v8 __attribute__((ext_vector_type(8)));
typedef unsigned short u16v4 __attribute__((ext_vector_type(4)));

union F4 { float4 v; float f[4]; };

__device__ __forceinline__ unsigned short f2bf(float v) {
    __hip_bfloat16 b = __float2bfloat16(v);
    return *reinterpret_cast<unsigned short*>(&b);
}
__device__ __forceinline__ float bf2f(unsigned short u) {
    __hip_bfloat16 b = *reinterpret_cast<__hip_bfloat16*>(&u);
    return __bfloat162float(b);
}

// ---------------------------------------------------------------------------
// convert_x: fp32 x -> hi/lo bf16 arrays [4096][768].
// ---------------------------------------------------------------------------
__global__ __launch_bounds__(256) void convert_x(
    const float* __restrict__ x,
    unsigned short* __restrict__ xh, unsigned short* __restrict__ xl)
{
    const size_t i0 = ((size_t)blockIdx.x * 256 + threadIdx.x) * 8;
    F4 a, b;
    a.v = *(const float4*)&x[i0];
    b.v = *(const float4*)&x[i0 + 4];
    u16v8 h, l;
    #pragma unroll
    for (int j = 0; j < 4; j++) {
        unsigned short hu = f2bf(a.f[j]);
        h[j] = hu; l[j] = f2bf(a.f[j] - bf2f(hu));
    }
    #pragma unroll
    for (int j = 0; j < 4; j++) {
        unsigned short hu = f2bf(b.f[j]);
        h[4+j] = hu; l[4+j] = f2bf(b.f[j] - bf2f(hu));
    }
    *(u16v8*)&xh[i0] = h;
    *(u16v8*)&xl[i0] = l;
}

// ---------------------------------------------------------------------------
// convert_wT: W [768 k][768 n] fp32 -> W^T hi/lo bf16 [mat][768 n][768 k].
// ---------------------------------------------------------------------------
__global__ __launch_bounds__(256) void convert_wT(
    const float* __restrict__ Wq, const float* __restrict__ Wk,
    const float* __restrict__ Wv, const float* __restrict__ Wo,
    unsigned short* __restrict__ WhT, unsigned short* __restrict__ WlT)
{
    const int z = blockIdx.z;
    const float* W = (z == 0) ? Wq : (z == 1) ? Wk : (z == 2) ? Wv : Wo;
    unsigned short* oh = WhT + (size_t)z * 589824;
    unsigned short* ol = WlT + (size_t)z * 589824;
    __shared__ float T[64][68];
    const int t = threadIdx.x;
    const int r = t >> 2, cg = (t & 3) * 16;
    const int k0 = blockIdx.x * 64, n0 = blockIdx.y * 64;
    #pragma unroll
    for (int i = 0; i < 4; i++) {
        float4 v = *(const float4*)&W[(size_t)(k0 + r) * EMB + n0 + cg + 4*i];
        *(float4*)&T[r][cg + 4*i] = v;
    }
    __syncthreads();
    #pragma unroll
    for (int i = 0; i < 4; i++) {
        u16v4 h, l;
        #pragma unroll
        for (int j = 0; j < 4; j++) {
            float v = T[cg + 4*i + j][r];
            unsigned short hu = f2bf(v);
            h[j] = hu; l[j] = f2bf(v - bf2f(hu));
        }
        *(u16v4*)&oh[(size_t)(n0 + r) * EMB + k0 + cg + 4*i] = h;
        *(u16v4*)&ol[(size_t)(n0 + r) * EMB + k0 + cg + 4*i] = l;
    }
}

// ---------------------------------------------------------------------------
// qkv_mfma: split-bf16 MFMA GEMM, C = x @ W + b.  (unchanged from R6)
// Q: 3-term, hi/lo out. K: 3-term, single bf16 out. V: 2-term, transposed out.
// ---------------------------------------------------------------------------
#define GA_HOFF 0
#define GA_LOFF 4096
#define GW_HOFF 8192
#define GW_LOFF 12288

__global__ __launch_bounds__(256) void qkv_mfma(
    const unsigned short* __restrict__ xh, const unsigned short* __restrict__ xl,
    const unsigned short* __restrict__ WhT, const unsigned short* __restrict__ WlT,
    const float* __restrict__ bq, const float* __restrict__ bk, const float* __restrict__ bv,
    unsigned short* __restrict__ Qh, unsigned short* __restrict__ Ql,
    unsigned short* __restrict__ Kb, unsigned short* __restrict__ Vt)
{
    const int which = blockIdx.z;
    const unsigned short* Wh = WhT + (size_t)which * 589824;
    const unsigned short* Wl = WlT + (size_t)which * 589824;
    const float* bias = (which == 0) ? bq : (which == 1) ? bk : bv;

    __shared__ __align__(16) unsigned short lds[16384];
    const int tid = threadIdx.x;
    const int lane = tid & 63, lo = lane & 15, h4 = lane >> 4;
    const int w = tid >> 6, wm = w & 1, wn = w >> 1;
    const int row0 = blockIdx.x * 128, col0 = blockIdx.y * 128;

    f32x4 acc[4][4];
    #pragma unroll
    for (int i = 0; i < 4; i++)
        #pragma unroll
        for (int j = 0; j < 4; j++) acc[i][j] = (f32x4){0.f, 0.f, 0.f, 0.f};

    const int c0 = tid * 2, c1 = c0 + 1;
    const int sr0 = c0 >> 2, sc0 = (c0 & 3) * 8;
    const int sr1 = c1 >> 2, sc1 = (c1 & 3) * 8;

    for (int k0 = 0; k0 < EMB; k0 += 32) {
        u16v8 a0h, a1h, a0l, a1l, w0h, w1h, w0l, w1l;
        a0h = *(const u16v8*)&xh[(size_t)(row0 + sr0) * EMB + k0 + sc0];
        a1h = *(const u16v8*)&xh[(size_t)(row0 + sr1) * EMB + k0 + sc1];
        w0h = *(const u16v8*)&Wh[(size_t)(col0 + sr0) * EMB + k0 + sc0];
        w1h = *(const u16v8*)&Wh[(size_t)(col0 + sr1) * EMB + k0 + sc1];
        w0l = *(const u16v8*)&Wl[(size_t)(col0 + sr0) * EMB + k0 + sc0];
        w1l = *(const u16v8*)&Wl[(size_t)(col0 + sr1) * EMB + k0 + sc1];
        if (which <= 1) {
            a0l = *(const u16v8*)&xl[(size_t)(row0 + sr0) * EMB + k0 + sc0];
            a1l = *(const u16v8*)&xl[(size_t)(row0 + sr1) * EMB + k0 + sc1];
        }
        __syncthreads();
        *(u16v8*)&lds[GA_HOFF + c0*8] = a0h;
        *(u16v8*)&lds[GA_HOFF + c1*8] = a1h;
        *(u16v8*)&lds[GW_HOFF + c0*8] = w0h;
        *(u16v8*)&lds[GW_HOFF + c1*8] = w1h;
        *(u16v8*)&lds[GW_LOFF + c0*8] = w0l;
        *(u16v8*)&lds[GW_LOFF + c1*8] = w1l;
        if (which <= 1) {
            *(u16v8*)&lds[GA_LOFF + c0*8] = a0l;
            *(u16v8*)&lds[GA_LOFF + c1*8] = a1l;
        }
        __syncthreads();

        bf16x8 ah[4];
        #pragma unroll
        for (int i = 0; i < 4; i++)
            ah[i] = *(const bf16x8*)&lds[GA_HOFF + (64*wm + 16*i + lo)*32 + 8*h4];
        #pragma unroll
        for (int j = 0; j < 4; j++) {
            bf16x8 whf = *(const bf16x8*)&lds[GW_HOFF + (64*wn + 16*j + lo)*32 + 8*h4];
            bf16x8 wlf = *(const bf16x8*)&lds[GW_LOFF + (64*wn + 16*j + lo)*32 + 8*h4];
            #pragma unroll
            for (int i = 0; i < 4; i++) {
                acc[i][j] = __builtin_amdgcn_mfma_f32_16x16x32_bf16(ah[i], whf, acc[i][j], 0, 0, 0);
                acc[i][j] = __builtin_amdgcn_mfma_f32_16x16x32_bf16(ah[i], wlf, acc[i][j], 0, 0, 0);
            }
        }
        if (which <= 1) {
            #pragma unroll
            for (int j = 0; j < 4; j++) {
                bf16x8 whf = *(const bf16x8*)&lds[GW_HOFF + (64*wn + 16*j + lo)*32 + 8*h4];
                #pragma unroll
                for (int i = 0; i < 4; i++) {
                    bf16x8 alf = *(const bf16x8*)&lds[GA_LOFF + (64*wm + 16*i + lo)*32 + 8*h4];
                    acc[i][j] = __builtin_amdgcn_mfma_f32_16x16x32_bf16(alf, whf, acc[i][j], 0, 0, 0);
                }
            }
        }
    }

    if (which == 0) {
        #pragma unroll
        for (int i = 0; i < 4; i++)
            #pragma unroll
            for (int r = 0; r < 4; r++) {
                const int sg = row0 + 64*wm + 16*i + 4*h4 + r;
                const int b = sg >> 11, s = sg & 2047;
                #pragma unroll
                for (int j = 0; j < 4; j++) {
                    const int c = col0 + 64*wn + 16*j + lo;
                    const int h = c / HD, d = c - h*HD;
                    float v = acc[i][j][r] + bias[c];
                    unsigned short hu = f2bf(v);
                    const size_t base = ((size_t)(b*NH + h) * SEQ + s) * HD + d;
                    Qh[base] = hu;
                    Ql[base] = f2bf(v - bf2f(hu));
                }
            }
    } else if (which == 1) {
        #pragma unroll
        for (int i = 0; i < 4; i++)
            #pragma unroll
            for (int r = 0; r < 4; r++) {
                const int sg = row0 + 64*wm + 16*i + 4*h4 + r;
                const int b = sg >> 11, s = sg & 2047;
                #pragma unroll
                for (int j = 0; j < 4; j++) {
                    const int c = col0 + 64*wn + 16*j + lo;
                    const int h = c / HD, d = c - h*HD;
                    float v = acc[i][j][r] + bias[c];
                    Kb[((size_t)(b*NH + h) * SEQ + s) * HD + d] = f2bf(v);
                }
            }
    } else {
        #pragma unroll
        for (int i = 0; i < 4; i++)
            #pragma unroll
            for (int r = 0; r < 4; r++) {
                const int sg = row0 + 64*wm + 16*i + 4*h4 + r;
                const int b = sg >> 11, s = sg & 2047;
                #pragma unroll
                for (int j = 0; j < 4; j++) {
                    const int c = col0 + 64*wn + 16*j + lo;
                    const int h = c / HD, d = c - h*HD;
                    float v = acc[i][j][r] + bias[c];
                    Vt[((size_t)(b*NH + h) * HD + d) * SEQ + s] = f2bf(v);
                }
            }
    }
}

// ---------------------------------------------------------------------------
// proj_mfma: out = AOh @ Wo + bo (fp32 out).  (unchanged)
// ---------------------------------------------------------------------------
#define PA_OFF 0
#define PWH_OFF 4096
#define PWL_OFF 8192

__global__ __launch_bounds__(256) void proj_mfma(
    const unsigned short* __restrict__ AOh,
    const unsigned short* __restrict__ Wh, const unsigned short* __restrict__ Wl,
    const float* __restrict__ bo, float* __restrict__ out)
{
    __shared__ __align__(16) unsigned short lds[12288];
    const int tid = threadIdx.x;
    const int lane = tid & 63, lo = lane & 15, h4 = lane >> 4;
    const int w = tid >> 6, wm = w & 1, wn = w >> 1;
    const int row0 = blockIdx.x * 128, col0 = blockIdx.y * 128;

    f32x4 acc[4][4];
    #pragma unroll
    for (int i = 0; i < 4; i++)
        #pragma unroll
        for (int j = 0; j < 4; j++) acc[i][j] = (f32x4){0.f, 0.f, 0.f, 0.f};

    const int c0 = tid * 2, c1 = c0 + 1;
    const int sr0 = c0 >> 2, sc0 = (c0 & 3) * 8;
    const int sr1 = c1 >> 2, sc1 = (c1 & 3) * 8;

    for (int k0 = 0; k0 < EMB; k0 += 32) {
        u16v8 a0, a1, w0h, w1h, w0l, w1l;
        a0  = *(const u16v8*)&AOh[(size_t)(row0 + sr0) * EMB + k0 + sc0];
        a1  = *(const u16v8*)&AOh[(size_t)(row0 + sr1) * EMB + k0 + sc1];
        w0h = *(const u16v8*)&Wh[(size_t)(col0 + sr0) * EMB + k0 + sc0];
        w1h = *(const u16v8*)&Wh[(size_t)(col0 + sr1) * EMB + k0 + sc1];
        w0l = *(const u16v8*)&Wl[(size_t)(col0 + sr0) * EMB + k0 + sc0];
        w1l = *(const u16v8*)&Wl[(size_t)(col0 + sr1) * EMB + k0 + sc1];
        __syncthreads();
        *(u16v8*)&lds[PA_OFF  + c0*8] = a0;
        *(u16v8*)&lds[PA_OFF  + c1*8] = a1;
        *(u16v8*)&lds[PWH_OFF + c0*8] = w0h;
        *(u16v8*)&lds[PWH_OFF + c1*8] = w1h;
        *(u16v8*)&lds[PWL_OFF + c0*8] = w0l;
        *(u16v8*)&lds[PWL_OFF + c1*8] = w1l;
        __syncthreads();

        bf16x8 af[4];
        #pragma unroll
        for (int i = 0; i < 4; i++)
            af[i] = *(const bf16x8*)&lds[PA_OFF + (64*wm + 16*i + lo)*32 + 8*h4];
        #pragma unroll
        for (int j = 0; j < 4; j++) {
            bf16x8 whf = *(const bf16x8*)&lds[PWH_OFF + (64*wn + 16*j + lo)*32 + 8*h4];
            bf16x8 wlf = *(const bf16x8*)&lds[PWL_OFF + (64*wn + 16*j + lo)*32 + 8*h4];
            #pragma unroll
            for (int i = 0; i < 4; i++) {
                acc[i][j] = __builtin_amdgcn_mfma_f32_16x16x32_bf16(af[i], whf, acc[i][j], 0, 0, 0);
                acc[i][j] = __builtin_amdgcn_mfma_f32_16x16x32_bf16(af[i], wlf, acc[i][j], 0, 0, 0);
            }
        }
    }

    #pragma unroll
    for (int i = 0; i < 4; i++)
        #pragma unroll
        for (int r = 0; r < 4; r++) {
            const int sg = row0 + 64*wm + 16*i + 4*h4 + r;
            #pragma unroll
            for (int j = 0; j < 4; j++) {
                const int c = col0 + 64*wn + 16*j + lo;
                out[(size_t)sg * EMB + c] = acc[i][j][r] + bo[c];
            }
        }
}

// ---------------------------------------------------------------------------
// Flash attention v4 = v3 + software-pipelined K (register double-buffer).
// The only zero-slack stall in v3 was K-frag loads feeding QK immediately;
// now chunk c issues chunk c+1's K (ks0/ks1 at top, ks2 after QK) and its own
// V in two halves -> every load gets >=400 cyc of compute cover. No numerics
// change. Peak VGPR ~236 (2 waves/SIMD, unchanged occupancy).
// ---------------------------------------------------------------------------
__device__ __forceinline__ void kload_all(bf16x8 (&dst)[12],
    const unsigned short* __restrict__ KbH, int kelem, int lo, int h4)
{
    const unsigned short* KG = KbH + (size_t)kelem * HD;
    #pragma unroll
    for (int ks = 0; ks < 3; ks++)
        #pragma unroll
        for (int nb = 0; nb < 4; nb++)
            dst[ks*4 + nb] = *(const bf16x8*)&KG[(size_t)(16*nb + lo)*HD + 32*ks + 8*h4];
}

__device__ __forceinline__ void attn_step(
    bf16x8 (&cur)[12], bf16x8 (&nxt)[12],
    const bf16x8 (&qhf)[2][3], const bf16x8 (&qlf)[2][3],
    f32x4 (&O)[2][6], float (&lsum)[2][4],
    unsigned short* __restrict__ Pw,
    const unsigned short* __restrict__ KbH,
    const unsigned short* __restrict__ VtH,
    int k0, int kn, int lo, int h4)
{
    const unsigned short* VtG = VtH + k0;
    const unsigned short* KnG = KbH + (size_t)kn * HD;

    bf16x8 vf[12];
    // V half 0 (key cols 0..31 of this chunk) — consumed at PV, ~800 cyc away
    #pragma unroll
    for (int nb2 = 0; nb2 < 6; nb2++)
        vf[nb2] = *(const bf16x8*)&VtG[(size_t)(16*nb2 + lo)*SEQ + 8*h4];
    // next-chunk K, ks groups 0..1 — consumed next chunk, ~1300 cyc away
    #pragma unroll
    for (int ks = 0; ks < 2; ks++)
        #pragma unroll
        for (int nb = 0; nb < 4; nb++)
            nxt[ks*4 + nb] = *(const bf16x8*)&KnG[(size_t)(16*nb + lo)*HD + 32*ks + 8*h4];

    // ---- QK mi=0 (cur K regs already resident) ----
    f32x4 S0[4];
    #pragma unroll
    for (int nb = 0; nb < 4; nb++) S0[nb] = (f32x4){0.f, 0.f, 0.f, 0.f};
    #pragma unroll
    for (int ks = 0; ks < 3; ks++)
        #pragma unroll
        for (int nb = 0; nb < 4; nb++) {
            S0[nb] = __builtin_amdgcn_mfma_f32_16x16x32_bf16(qhf[0][ks], cur[ks*4+nb], S0[nb], 0, 0, 0);
            S0[nb] = __builtin_amdgcn_mfma_f32_16x16x32_bf16(qlf[0][ks], cur[ks*4+nb], S0[nb], 0, 0, 0);
        }
    // ---- exp mi=0 -> P rows 0..15 ----
    #pragma unroll
    for (int nb = 0; nb < 4; nb++)
        #pragma unroll
        for (int r = 0; r < 4; r++) {
            float p = __expf(S0[nb][r]);
            lsum[0][r] += p;
            Pw[(4*h4 + r)*72 + 16*nb + lo] = f2bf(p);
        }

    // ---- QK mi=1 ----
    f32x4 S1[4];
    #pragma unroll
    for (int nb = 0; nb < 4; nb++) S1[nb] = (f32x4){0.f, 0.f, 0.f, 0.f};
    #pragma unroll
    for (int ks = 0; ks < 3; ks++)
        #pragma unroll
        for (int nb = 0; nb < 4; nb++) {
            S1[nb] = __builtin_amdgcn_mfma_f32_16x16x32_bf16(qhf[1][ks], cur[ks*4+nb], S1[nb], 0, 0, 0);
            S1[nb] = __builtin_amdgcn_mfma_f32_16x16x32_bf16(qlf[1][ks], cur[ks*4+nb], S1[nb], 0, 0, 0);
        }

    // cur K now dead: issue next-chunk K ks group 2 + V half 1
    #pragma unroll
    for (int nb = 0; nb < 4; nb++)
        nxt[8 + nb] = *(const bf16x8*)&KnG[(size_t)(16*nb + lo)*HD + 64 + 8*h4];
    #pragma unroll
    for (int nb2 = 0; nb2 < 6; nb2++)
        vf[6 + nb2] = *(const bf16x8*)&VtG[(size_t)(16*nb2 + lo)*SEQ + 32 + 8*h4];

    // ---- exp mi=1 -> P rows 16..31 ----
    #pragma unroll
    for (int nb = 0; nb < 4; nb++)
        #pragma unroll
        for (int r = 0; r < 4; r++) {
            float p = __expf(S1[nb][r]);
            lsum[1][r] += p;
            Pw[(16 + 4*h4 + r)*72 + 16*nb + lo] = f2bf(p);
        }

    // ---- O += P V ----
    #pragma unroll
    for (int ks2 = 0; ks2 < 2; ks2++) {
        bf16x8 pf0 = *(const bf16x8*)&Pw[(lo)*72      + 32*ks2 + 8*h4];
        bf16x8 pf1 = *(const bf16x8*)&Pw[(16 + lo)*72 + 32*ks2 + 8*h4];
        #pragma unroll
        for (int nb2 = 0; nb2 < 6; nb2++) {
            O[0][nb2] = __builtin_amdgcn_mfma_f32_16x16x32_bf16(pf0, vf[6*ks2 + nb2], O[0][nb2], 0, 0, 0);
            O[1][nb2] = __builtin_amdgcn_mfma_f32_16x16x32_bf16(pf1, vf[6*ks2 + nb2], O[1][nb2], 0, 0, 0);
        }
    }
}

__global__ __launch_bounds__(128, 2) void attn_mfma(
    const unsigned short* __restrict__ Qh, const unsigned short* __restrict__ Ql,
    const unsigned short* __restrict__ Kb, const unsigned short* __restrict__ Vt,
    unsigned short* __restrict__ AOh)
{
    __shared__ __align__(16) unsigned short lds[11072];  // P: 2x2304 | Cbuf 3200f + Lbuf 32f
    const int id   = blockIdx.x;
    const int bh   = 2*(id & 7) + ((id >> 3) & 1);   // XCD-pinned: 2 heads per XCD
    const int qb   = id >> 4;                        // 0..63
    const int q0   = qb * 32;
    const int tid  = threadIdx.x;                    // 0..127
    const int wk   = tid >> 6;                       // k-half
    const int lane = tid & 63;
    const int lo   = lane & 15;
    const int h4   = lane >> 4;

    bf16x8 qhf[2][3], qlf[2][3];
    #pragma unroll
    for (int mi = 0; mi < 2; mi++) {
        const size_t qoff = ((size_t)bh*SEQ + q0 + 16*mi + lo) * HD + 8*h4;
        #pragma unroll
        for (int ks = 0; ks < 3; ks++) {
            qhf[mi][ks] = *(const bf16x8*)&Qh[qoff + 32*ks];
            qlf[mi][ks] = *(const bf16x8*)&Ql[qoff + 32*ks];
        }
    }

    f32x4 O[2][6];
    #pragma unroll
    for (int mi = 0; mi < 2; mi++)
        #pragma unroll
        for (int i = 0; i < 6; i++) O[mi][i] = (f32x4){0.f, 0.f, 0.f, 0.f};
    float lsum[2][4] = {};

    unsigned short* Pw = lds + wk * 2304;            // wave-private [32][72]
    const unsigned short* KbH = Kb + (size_t)bh * SEQ * HD;
    const unsigned short* VtH = Vt + (size_t)bh * HD * SEQ;

    bf16x8 kA[12], kB[12];
    kload_all(kA, KbH, (wk*16)*64, lo, h4);

    #pragma unroll 1
    for (int cc = 0; cc < 16; cc += 2) {
        const int k0a = (wk*16 + cc) * 64;
        const int k0b = (wk*16 + cc + 1) * 64;
        const int k0c = (cc + 2 < 16) ? (wk*16 + cc + 2) * 64 : (wk*16) * 64;  // tail clamp
        attn_step(kA, kB, qhf, qlf, O, lsum, Pw, KbH, VtH, k0a, k0b, lo, h4);
        attn_step(kB, kA, qhf, qlf, O, lsum, Pw, KbH, VtH, k0b, k0c, lo, h4);
    }

    // ---- split-K combine (single barrier) ----
    float lred[2][4];
    #pragma unroll
    for (int mi = 0; mi < 2; mi++)
        #pragma unroll
        for (int r = 0; r < 4; r++) {
            float l = lsum[mi][r];
            l += __shfl_xor(l, 1);
            l += __shfl_xor(l, 2);
            l += __shfl_xor(l, 4);
            l += __shfl_xor(l, 8);
            lred[mi][r] = l;
        }

    float* Cbuf = (float*)(lds + 4608);   // [32][100]
    float* Lbuf = Cbuf + 3200;            // [32]
    if (wk == 1) {
        #pragma unroll
        for (int mi = 0; mi < 2; mi++)
            #pragma unroll
            for (int r = 0; r < 4; r++) {
                const int row = 16*mi + 4*h4 + r;
                if (lo == 0) Lbuf[row] = lred[mi][r];
                #pragma unroll
                for (int nb2 = 0; nb2 < 6; nb2++)
                    Cbuf[row*100 + 16*nb2 + lo] = O[mi][nb2][r];
            }
    }
    __syncthreads();
    if (wk == 0) {
        const int b = bh >> 3, hh = bh & 7;
        #pragma unroll
        for (int mi = 0; mi < 2; mi++)
            #pragma unroll
            for (int r = 0; r < 4; r++) {
                const int row = 16*mi + 4*h4 + r;
                const float lt = lred[mi][r] + Lbuf[row];
                const float sc = SCALING / lt;
                const int q = q0 + row;
                const size_t base = ((size_t)b*SEQ + q)*EMB + hh*HD + lo;
                #pragma unroll
                for (int nb2 = 0; nb2 < 6; nb2++)
                    AOh[base + 16*nb2] =
                        f2bf((O[mi][nb2][r] + Cbuf[row*100 + 16*nb2 + lo]) * sc);
            }
    }
}

// ---------------------------------------------------------------------------
extern "C" void kernel_launch(void* const* d_in, const int* in_sizes, int n_in,
                              void* d_out, int out_size, void* d_ws, size_t ws_size,
                              hipStream_t stream)
{
    const float* x  = (const float*)d_in[0];
    const float* Wq = (const float*)d_in[1];
    const float* bq = (const float*)d_in[2];
    const float* Wk = (const float*)d_in[3];
    const float* bk = (const float*)d_in[4];
    const float* Wv = (const float*)d_in[5];
    const float* bv = (const float*)d_in[6];
    const float* Wo = (const float*)d_in[7];
    const float* bo = (const float*)d_in[8];
    float* out = (float*)d_out;

    unsigned short* ws = (unsigned short*)d_ws;
    const size_t HS = (size_t)16 * SEQ * HD;       // 3,145,728 shorts
    const size_t WS1 = (size_t)EMB * EMB;          // 589,824
    unsigned short* Qh  = ws;
    unsigned short* Ql  = ws + HS;
    unsigned short* Kb  = ws + 2*HS;
    unsigned short* Vt  = ws + 3*HS;
    unsigned short* xh  = ws + 4*HS;               // dead after qkv -> AOh
    unsigned short* xl  = ws + 5*HS;
    unsigned short* WhT = ws + 6*HS;
    unsigned short* WlT = ws + 6*HS + 4*WS1;
    unsigned short* AOh = xh;

    convert_x<<<1536, 256, 0, stream>>>(x, xh, xl);
    convert_wT<<<dim3(12, 12, 4), 256, 0, stream>>>(Wq, Wk, Wv, Wo, WhT, WlT);
    qkv_mfma<<<dim3(32, 6, 3), 256, 0, stream>>>(xh, xl, WhT, WlT, bq, bk, bv,
                                                 Qh, Ql, Kb, Vt);
    attn_mfma<<<1024, 128, 0, stream>>>(Qh, Ql, Kb, Vt, AOh);
    proj_mfma<<<dim3(32, 6), 256, 0, stream>>>(AOh, WhT + 3*WS1, WlT + 3*WS1, bo, out);
}